// Round 3
// baseline (162.814 us; speedup 1.0000x reference)
//
#include <hip/hip_runtime.h>
#include <hip/hip_bf16.h>

#define IMG_W 1024
#define IMG_H 1024
#define TH    8           // output rows per block: 2048 blocks -> 8 blocks/CU
#define VX    4           // pixels per thread (float4)
#define NTHREADS 256      // 256*4 = 1024 = full row width

#define ALPHA_ 0.85f
#define BETA_  0.15f
#define C1_    (0.01f * 0.01f)
#define C2_    (0.03f * 0.03f)

// Sums-domain SSIM constants (numerator/denominator both scaled by 81).
#define K1_   (81.0f * C1_)          // 0.0081
#define K2_   (81.0f * C2_)          // 0.0729
#define K12_  (K1_ + K2_)            // 0.081

// Counted-vmcnt + raw-barrier phase boundary (T3/T4 pattern).
// sched_barrier(0) on both sides: (1) keeps the following DMA issue from
// being hoisted above the barrier, (2) keeps ds_reads from being hoisted
// above it, (3) stops the scheduler from cross-mixing phases (which is what
// defeated the R1/R2 register prefetch).
#define WAITBAR(N) do {                                        \
    asm volatile("s_waitcnt vmcnt(" #N ")" ::: "memory");      \
    __builtin_amdgcn_sched_barrier(0);                         \
    __builtin_amdgcn_s_barrier();                              \
    __builtin_amdgcn_sched_barrier(0);                         \
} while (0)

// Pin the DMA issue point: everything before this stays before it.
#define PIN() __builtin_amdgcn_sched_barrier(0)

// Per-row horizontal 3-sum stats for VX pixels: 20 floats.
struct RowS { float p[VX], t[VX], pp[VX], tt[VX], pt[VX]; };

__device__ __forceinline__ void rzero(RowS& h) {
#pragma unroll
    for (int j = 0; j < VX; ++j) {
        h.p[j] = 0.f; h.t[j] = 0.f; h.pp[j] = 0.f; h.tt[j] = 0.f; h.pt[j] = 0.f;
    }
}

// Read 6 consecutive pixels (x-1 .. x+4) of one staged row from LDS.
// Image-edge columns get zero (matches zero-pad semantics). Addresses are
// clamped BEFORE the read so no negative/OOB LDS address is ever formed.
__device__ __forceinline__ void lds_read6(const float* __restrict__ row, int x,
                                          float v[6]) {
    const float4 m = *reinterpret_cast<const float4*>(row + x);   // ds_read_b128
    v[1] = m.x; v[2] = m.y; v[3] = m.z; v[4] = m.w;
    const int xl = (x > 0) ? x - 1 : 0;
    const int xr = (x + VX < IMG_W) ? x + VX : IMG_W - 1;
    float l = row[xl];                 // ds_read_b32 (may 8-way alias banks;
    float r = row[xr];                 //  if SQ_LDS_BANK_CONFLICT blows up,
    if (x == 0)            l = 0.f;    //  switch these to __shfl)
    if (x + VX >= IMG_W)   r = 0.f;
    v[0] = l; v[5] = r;
}

__device__ __forceinline__ void hsum(const float pv[6], const float tv[6], RowS& h) {
#pragma unroll
    for (int j = 0; j < VX; ++j) {
        const float a = pv[j], b = pv[j + 1], c = pv[j + 2];
        const float u = tv[j], v = tv[j + 1], w = tv[j + 2];
        h.p[j]  = a + b + c;
        h.t[j]  = u + v + w;
        h.pp[j] = a * a + b * b + c * c;
        h.tt[j] = u * u + v * v + w * w;
        h.pt[j] = a * u + b * v + c * w;
    }
}

__device__ __forceinline__ void add_l1(const float pv[6], const float tv[6],
                                       float& l1_acc) {
#pragma unroll
    for (int k = 1; k <= VX; ++k) l1_acc += fabsf(pv[k] - tv[k]);
}

// Consume one row: emit SSIM for the output row above it and roll the
// vertical window state (AB = rowstats(y-1)+rowstats(y), Bp = rowstats(y)).
__device__ __forceinline__ void compute_row(const float pv[6], const float tv[6],
                                            RowS& AB, RowS& Bp, float& ssim_acc) {
#pragma unroll
    for (int j = 0; j < VX; ++j) {
        const float a = pv[j], b = pv[j + 1], c = pv[j + 2];
        const float u = tv[j], v = tv[j + 1], w = tv[j + 2];
        const float cp  = a + b + c;
        const float ct  = u + v + w;
        const float cpp = a * a + b * b + c * c;
        const float ctt = u * u + v * v + w * w;
        const float cpt = a * u + b * v + c * w;

        const float Sp  = AB.p[j]  + cp;
        const float St  = AB.t[j]  + ct;
        const float Spp = AB.pp[j] + cpp;
        const float Stt = AB.tt[j] + ctt;
        const float Spt = AB.pt[j] + cpt;

        AB.p[j]  = Bp.p[j]  + cp;  Bp.p[j]  = cp;
        AB.t[j]  = Bp.t[j]  + ct;  Bp.t[j]  = ct;
        AB.pp[j] = Bp.pp[j] + cpp; Bp.pp[j] = cpp;
        AB.tt[j] = Bp.tt[j] + ctt; Bp.tt[j] = ctt;
        AB.pt[j] = Bp.pt[j] + cpt; Bp.pt[j] = cpt;

        // sums-domain SSIM (x81^2 in both numerator and denominator)
        const float SpSt = Sp * St;
        const float A2 = fmaf(2.0f, SpSt, K1_);
        const float B2 = fmaf(-2.0f, SpSt, fmaf(18.0f, Spt, K2_));
        const float n  = A2 * B2;
        const float D1 = fmaf(Sp, Sp, fmaf(St, St, K1_));
        const float D2 = fmaf(9.0f, Spp + Stt, K12_) - D1;
        const float d  = D1 * D2;
        const float ssim = n * __builtin_amdgcn_rcpf(d);  // d >= 81^2*C1*C2 > 0
        float vcl = fmaf(-0.5f, ssim, 0.5f);
        vcl = fminf(fmaxf(vcl, 0.0f), 1.0f);
        ssim_acc += vcl;
    }
}

// R3 structure: async LDS staging via global_load_lds (scheduler-proof
// prefetch: no VGPR destination for the allocator to sink).
// - 3 row slots per tensor in LDS (24 KiB/block -> 6 blocks/CU).
// - Phase r: WAITBAR(vmcnt=2) ; stage row r+2 -> slot (r+2)%3 ; compute row
//   r from slot r%3.  vmcnt(2) leaves exactly row r+1's two loads in flight
//   (counted wait, never 0 until the final phase).
// Race-freedom of the single barrier per phase:
//  * slot written at phase r is (r+2)%3; readers at phase r read r%3 (!=).
//  * stale readers of slot (r+2)%3 were at phase r-1 (slot (r-1)%3 ==
//    (r+2)%3) — they consumed all ds_read values BEFORE the phase-r barrier
//    (every loaded value feeds compute before the barrier), and the DMA for
//    slot (r+2)%3 is issued only AFTER the phase-r barrier. Ordered.
//  * cross-wave halo elements (quarter boundaries): each wave's vmcnt wait
//    puts its own quarter in LDS before it passes the barrier, so neighbor
//    waves' post-barrier reads see it.
template <int MODE>
__global__ void __launch_bounds__(NTHREADS)
ssim_l1_kernel(const float* __restrict__ pred, const float* __restrict__ tgt,
               float* __restrict__ ws) {
    __shared__ __align__(16) float pbuf[3][IMG_W];
    __shared__ __align__(16) float tbuf[3][IMG_W];
    __shared__ float red_s[NTHREADS / 64];
    __shared__ float red_l[NTHREADS / 64];

    const int tid  = threadIdx.x;
    const int x    = tid * VX;
    const int wq   = (tid >> 6) * (64 * VX);   // wave-uniform quarter offset (floats)
    const int y0   = blockIdx.y * TH;
    const size_t base = (size_t)blockIdx.z * (size_t)(IMG_W * IMG_H);
    const float* __restrict__ P = pred + base;
    const float* __restrict__ T = tgt + base;

    // Stage one image row (clamped) into LDS slot. Global addr is per-lane;
    // LDS dest is wave-uniform base; HW adds lane*16B.
    auto stage = [&](int rr, int slot) {
        int rc = rr;
        if (rc < 0) rc = 0;
        if (rc > IMG_H - 1) rc = IMG_H - 1;
        const float* gp = P + (size_t)rc * IMG_W + x;
        const float* gt = T + (size_t)rc * IMG_W + x;
        __builtin_amdgcn_global_load_lds(
            (const __attribute__((address_space(1))) void*)gp,
            (__attribute__((address_space(3))) void*)(&pbuf[slot][wq]), 16, 0, 0);
        __builtin_amdgcn_global_load_lds(
            (const __attribute__((address_space(1))) void*)gt,
            (__attribute__((address_space(3))) void*)(&tbuf[slot][wq]), 16, 0, 0);
    };

    float ssim_acc = 0.f, l1_acc = 0.f;
    RowS AB, Bp;
    float pv[6], tv[6];

    // prologue: rows for phases 0 and 1
    stage(y0 - 1, 0);
    stage(y0,     1);

    // phase 0: row y0-1 (top halo) -> AB (or zeros at image top)
    WAITBAR(2);
    stage(y0 + 1, 2);
    PIN();
    if (y0 > 0) {
        lds_read6(pbuf[0], x, pv);
        lds_read6(tbuf[0], x, tv);
        hsum(pv, tv, AB);
    } else {
        rzero(AB);
    }

    // phase 1: row y0 -> Bp; AB += Bp; l1
    WAITBAR(2);
    stage(y0 + 2, 0);
    PIN();
    lds_read6(pbuf[1], x, pv);
    lds_read6(tbuf[1], x, tv);
    hsum(pv, tv, Bp);
    add_l1(pv, tv, l1_acc);
#pragma unroll
    for (int j = 0; j < VX; ++j) {
        AB.p[j]  += Bp.p[j];  AB.t[j]  += Bp.t[j];
        AB.pp[j] += Bp.pp[j]; AB.tt[j] += Bp.tt[j]; AB.pt[j] += Bp.pt[j];
    }

    // phases 2..7: rows y0+1 .. y0+6 (all in-bounds; stage rows y0+3..y0+8)
#pragma unroll
    for (int r = 2; r <= 7; ++r) {
        WAITBAR(2);
        stage(y0 + r + 1, (r + 2) % 3);
        PIN();
        const int slot = r % 3;
        lds_read6(pbuf[slot], x, pv);
        lds_read6(tbuf[slot], x, tv);
        add_l1(pv, tv, l1_acc);
        compute_row(pv, tv, AB, Bp, ssim_acc);
    }

    // phase 8: row y0+7 (slot 2) — no further staging
    WAITBAR(2);
    {
        lds_read6(pbuf[2], x, pv);
        lds_read6(tbuf[2], x, tv);
        add_l1(pv, tv, l1_acc);
        compute_row(pv, tv, AB, Bp, ssim_acc);
    }

    // phase 9: row y0+8 (slot 0) — bottom halo; zeros past the image edge
    WAITBAR(0);
    if (y0 + TH < IMG_H) {
        lds_read6(pbuf[0], x, pv);
        lds_read6(tbuf[0], x, tv);
    } else {
#pragma unroll
        for (int k = 0; k < 6; ++k) { pv[k] = 0.f; tv[k] = 0.f; }
    }
    compute_row(pv, tv, AB, Bp, ssim_acc);   // halo row: no l1

    // --- reduction: wave shuffle -> LDS across 4 waves -> one write/block ---
    float s = ssim_acc, l = l1_acc;
#pragma unroll
    for (int off = 32; off > 0; off >>= 1) {
        s += __shfl_down(s, off, 64);
        l += __shfl_down(l, off, 64);
    }
    const int wid = tid >> 6, lane = tid & 63;
    if (lane == 0) { red_s[wid] = s; red_l[wid] = l; }
    __syncthreads();
    if (tid == 0) {
        float ss = 0.f, ll = 0.f;
#pragma unroll
        for (int w = 0; w < NTHREADS / 64; ++w) { ss += red_s[w]; ll += red_l[w]; }
        if (MODE == 0) {
            const int bid = blockIdx.z * gridDim.y + blockIdx.y;
            ws[2 * bid]     = ss;   // every slot written every call: no pre-zero
            ws[2 * bid + 1] = ll;
        } else {
            atomicAdd(&ws[0], ss);
            atomicAdd(&ws[1], ll);
        }
    }
}

__global__ void zero_ws_kernel(float* __restrict__ ws) {
    ws[0] = 0.f;
    ws[1] = 0.f;
}

// Sum nblocks (ssim,l1) pairs from ws and emit the final scalar.
__global__ void __launch_bounds__(256)
finalize_partials_kernel(const float* __restrict__ ws, float* __restrict__ out,
                         int nblocks, float inv_total) {
    const int tid = threadIdx.x;
    float s = 0.f, l = 0.f;
    for (int i = tid; i < nblocks; i += 256) {
        s += ws[2 * i];
        l += ws[2 * i + 1];
    }
#pragma unroll
    for (int off = 32; off > 0; off >>= 1) {
        s += __shfl_down(s, off, 64);
        l += __shfl_down(l, off, 64);
    }
    __shared__ float red_s[4], red_l[4];
    const int wid = tid >> 6, lane = tid & 63;
    if (lane == 0) { red_s[wid] = s; red_l[wid] = l; }
    __syncthreads();
    if (tid == 0) {
        float ss = red_s[0] + red_s[1] + red_s[2] + red_s[3];
        float ll = red_l[0] + red_l[1] + red_l[2] + red_l[3];
        out[0] = ALPHA_ * (ss * inv_total) + BETA_ * (ll * inv_total);
    }
}

__global__ void finalize_atomic_kernel(const float* __restrict__ ws,
                                       float* __restrict__ out, float inv_total) {
    out[0] = ALPHA_ * (ws[0] * inv_total) + BETA_ * (ws[1] * inv_total);
}

extern "C" void kernel_launch(void* const* d_in, const int* in_sizes, int n_in,
                              void* d_out, int out_size, void* d_ws, size_t ws_size,
                              hipStream_t stream) {
    const float* pred = (const float*)d_in[0];
    const float* tgt  = (const float*)d_in[1];
    float* ws = (float*)d_ws;

    const int total = in_sizes[0];                 // N * H * W = 16 * 1024 * 1024
    const int nimg  = total / (IMG_W * IMG_H);     // 16
    const int nblk  = nimg * (IMG_H / TH);         // 16 * 128 = 2048
    const float inv_total = 1.0f / (float)total;

    dim3 grid(1, IMG_H / TH, nimg);

    if (ws_size >= (size_t)(2 * nblk) * sizeof(float)) {
        // partials path: no pre-zero, no atomics
        ssim_l1_kernel<0><<<grid, NTHREADS, 0, stream>>>(pred, tgt, ws);
        finalize_partials_kernel<<<1, 256, 0, stream>>>(ws, (float*)d_out,
                                                        nblk, inv_total);
    } else {
        // fallback: atomic accumulation into ws[0..1]
        zero_ws_kernel<<<1, 1, 0, stream>>>(ws);
        ssim_l1_kernel<1><<<grid, NTHREADS, 0, stream>>>(pred, tgt, ws);
        finalize_atomic_kernel<<<1, 1, 0, stream>>>(ws, (float*)d_out, inv_total);
    }
}

// Round 4
// 147.502 us; speedup vs baseline: 1.1038x; 1.1038x over previous
//
#include <hip/hip_runtime.h>
#include <hip/hip_bf16.h>

#define IMG_W 1024
#define IMG_H 1024
#define TH    8           // output rows per block: 2048 blocks -> 8 blocks/CU
#define VX    4           // pixels per thread (float4)
#define NTHREADS 256      // 256*4 = 1024 = full row width

#define ALPHA_ 0.85f
#define BETA_  0.15f
#define C1_    (0.01f * 0.01f)
#define C2_    (0.03f * 0.03f)

// Sums-domain SSIM constants (numerator/denominator both scaled by 81).
#define K1_   (81.0f * C1_)          // 0.0081
#define K2_   (81.0f * C2_)          // 0.0729
#define K12_  (K1_ + K2_)            // 0.081

// Phase-boundary pin: loads issued above this line stay above the computes
// below it. Coarse (one per superphase) — NOT per-instruction pinning (m141
// lesson: fine-grained sched_barrier(0) defeats the scheduler; coarse
// region boundaries preserve its freedom within each region).
#define PIN() __builtin_amdgcn_sched_barrier(0)

// Per-row horizontal 3-sum stats for VX pixels: 20 floats.
struct RowS { float p[VX], t[VX], pp[VX], tt[VX], pt[VX]; };

__device__ __forceinline__ void rzero(RowS& h) {
#pragma unroll
    for (int j = 0; j < VX; ++j) {
        h.p[j] = 0.f; h.t[j] = 0.f; h.pp[j] = 0.f; h.tt[j] = 0.f; h.pt[j] = 0.f;
    }
}

__device__ __forceinline__ void load_row(const float* __restrict__ Pr,
                                         const float* __restrict__ Tr,
                                         int x, float pv[6], float tv[6]) {
    const float4 p4 = *reinterpret_cast<const float4*>(Pr + x);
    const float4 t4 = *reinterpret_cast<const float4*>(Tr + x);
    pv[1] = p4.x; pv[2] = p4.y; pv[3] = p4.z; pv[4] = p4.w;
    tv[1] = t4.x; tv[2] = t4.y; tv[3] = t4.z; tv[4] = t4.w;
    pv[0] = (x > 0)          ? Pr[x - 1]  : 0.f;   // zero-pad at image left edge
    pv[5] = (x + VX < IMG_W) ? Pr[x + VX] : 0.f;   // zero-pad at image right edge
    tv[0] = (x > 0)          ? Tr[x - 1]  : 0.f;
    tv[5] = (x + VX < IMG_W) ? Tr[x + VX] : 0.f;
}

__device__ __forceinline__ void zero6(float pv[6], float tv[6]) {
#pragma unroll
    for (int k = 0; k < 6; ++k) { pv[k] = 0.f; tv[k] = 0.f; }
}

__device__ __forceinline__ void hsum(const float pv[6], const float tv[6], RowS& h) {
#pragma unroll
    for (int j = 0; j < VX; ++j) {
        const float a = pv[j], b = pv[j + 1], c = pv[j + 2];
        const float u = tv[j], v = tv[j + 1], w = tv[j + 2];
        h.p[j]  = a + b + c;
        h.t[j]  = u + v + w;
        h.pp[j] = a * a + b * b + c * c;
        h.tt[j] = u * u + v * v + w * w;
        h.pt[j] = a * u + b * v + c * w;
    }
}

__device__ __forceinline__ void add_l1(const float pv[6], const float tv[6],
                                       float& l1_acc) {
#pragma unroll
    for (int k = 1; k <= VX; ++k) l1_acc += fabsf(pv[k] - tv[k]);
}

// Consume one row: emit SSIM for the output row above it and roll the
// vertical window state (AB = rowstats(y-1)+rowstats(y), Bp = rowstats(y)).
__device__ __forceinline__ void compute_row(const float pv[6], const float tv[6],
                                            RowS& AB, RowS& Bp, float& ssim_acc) {
#pragma unroll
    for (int j = 0; j < VX; ++j) {
        const float a = pv[j], b = pv[j + 1], c = pv[j + 2];
        const float u = tv[j], v = tv[j + 1], w = tv[j + 2];
        const float cp  = a + b + c;
        const float ct  = u + v + w;
        const float cpp = a * a + b * b + c * c;
        const float ctt = u * u + v * v + w * w;
        const float cpt = a * u + b * v + c * w;

        const float Sp  = AB.p[j]  + cp;
        const float St  = AB.t[j]  + ct;
        const float Spp = AB.pp[j] + cpp;
        const float Stt = AB.tt[j] + ctt;
        const float Spt = AB.pt[j] + cpt;

        AB.p[j]  = Bp.p[j]  + cp;  Bp.p[j]  = cp;
        AB.t[j]  = Bp.t[j]  + ct;  Bp.t[j]  = ct;
        AB.pp[j] = Bp.pp[j] + cpp; Bp.pp[j] = cpp;
        AB.tt[j] = Bp.tt[j] + ctt; Bp.tt[j] = ctt;
        AB.pt[j] = Bp.pt[j] + cpt; Bp.pt[j] = cpt;

        // sums-domain SSIM (x81^2 in both numerator and denominator)
        const float SpSt = Sp * St;
        const float A2 = fmaf(2.0f, SpSt, K1_);
        const float B2 = fmaf(-2.0f, SpSt, fmaf(18.0f, Spt, K2_));
        const float n  = A2 * B2;
        const float D1 = fmaf(Sp, Sp, fmaf(St, St, K1_));
        const float D2 = fmaf(9.0f, Spp + Stt, K12_) - D1;
        const float d  = D1 * D2;
        const float ssim = n * __builtin_amdgcn_rcpf(d);  // d >= 81^2*C1*C2 > 0
        float vcl = fmaf(-0.5f, ssim, 0.5f);
        vcl = fminf(fmaxf(vcl, 0.0f), 1.0f);
        ssim_acc += vcl;
    }
}

// R4 structure: deep register pipeline. 6 row buffers (B0..B5), straight-line
// 2-row superphases; loads for a superphase are issued TWO superphases before
// consumption (>= 4 rows / ~8 KB in flight per wave in steady state), with a
// single sched_barrier(0) pin at each load/compute boundary so the scheduler
// cannot sink the loads (R1/R2 had no order enforcement; R3's LDS+barrier
// variant paid 2M bank-conflict cycles + 10 workgroup barriers -> reverted).
// Theory: system-wide burst queueing stretches load round-trips to ~2.4 us;
// throughput = in-flight-bytes / latency, so doubling per-wave in-flight
// bytes should raise delivered BW proportionally.
template <int MODE>
__global__ void __launch_bounds__(NTHREADS)
ssim_l1_kernel(const float* __restrict__ pred, const float* __restrict__ tgt,
               float* __restrict__ ws) {
    const int tid = threadIdx.x;
    const int x   = tid * VX;
    const int y0  = blockIdx.y * TH;
    const size_t base = (size_t)blockIdx.z * (size_t)(IMG_W * IMG_H);
    const float* __restrict__ P = pred + base;
    const float* __restrict__ T = tgt + base;

    float ssim_acc = 0.f, l1_acc = 0.f;
    RowS AB, Bp;
    float pv0[6], tv0[6], pv1[6], tv1[6], pv2[6], tv2[6];
    float pv3[6], tv3[6], pv4[6], tv4[6], pv5[6], tv5[6];

#define LOADB(pb, tb, rr) \
    load_row(P + (size_t)(rr) * IMG_W, T + (size_t)(rr) * IMG_W, x, pb, tb)

    // ---- pre: rows y0-1 .. y0+2 -> B0..B3 (4 rows in flight) ----
    LOADB(pv0, tv0, (y0 > 0 ? y0 - 1 : 0));   // clamped; discarded via rzero if y0==0
    LOADB(pv1, tv1, y0);
    LOADB(pv2, tv2, y0 + 1);
    LOADB(pv3, tv3, y0 + 2);
    PIN();

    // ---- S0: issue y0+3,y0+4 -> B4,B5 ; consume B0,B1 (prologue rows) ----
    LOADB(pv4, tv4, y0 + 3);
    LOADB(pv5, tv5, y0 + 4);
    PIN();
    if (y0 > 0) {
        hsum(pv0, tv0, AB);
    } else {
        rzero(AB);
    }
    hsum(pv1, tv1, Bp);
    add_l1(pv1, tv1, l1_acc);
#pragma unroll
    for (int j = 0; j < VX; ++j) {
        AB.p[j]  += Bp.p[j];  AB.t[j]  += Bp.t[j];
        AB.pp[j] += Bp.pp[j]; AB.tt[j] += Bp.tt[j]; AB.pt[j] += Bp.pt[j];
    }

    // ---- S1: issue y0+5,y0+6 -> B0,B1 ; consume B2,B3 (rows y0+1,y0+2) ----
    LOADB(pv0, tv0, y0 + 5);
    LOADB(pv1, tv1, y0 + 6);
    PIN();
    add_l1(pv2, tv2, l1_acc);
    compute_row(pv2, tv2, AB, Bp, ssim_acc);    // row y0+1
    add_l1(pv3, tv3, l1_acc);
    compute_row(pv3, tv3, AB, Bp, ssim_acc);    // row y0+2

    // ---- S2: issue y0+7,(y0+8) -> B2,B3 ; consume B4,B5 (rows y0+3,y0+4) ----
    LOADB(pv2, tv2, y0 + 7);
    if (y0 + TH < IMG_H) {
        LOADB(pv3, tv3, y0 + TH);       // bottom halo row
    } else {
        zero6(pv3, tv3);                // image bottom: zero-pad (uniform branch)
    }
    PIN();
    add_l1(pv4, tv4, l1_acc);
    compute_row(pv4, tv4, AB, Bp, ssim_acc);    // row y0+3
    add_l1(pv5, tv5, l1_acc);
    compute_row(pv5, tv5, AB, Bp, ssim_acc);    // row y0+4

    // ---- S3: consume B0,B1 (rows y0+5,y0+6) ----
    add_l1(pv0, tv0, l1_acc);
    compute_row(pv0, tv0, AB, Bp, ssim_acc);    // row y0+5
    add_l1(pv1, tv1, l1_acc);
    compute_row(pv1, tv1, AB, Bp, ssim_acc);    // row y0+6

    // ---- S4: consume B2,B3 (rows y0+7, y0+8-halo) ----
    add_l1(pv2, tv2, l1_acc);
    compute_row(pv2, tv2, AB, Bp, ssim_acc);    // row y0+7
    compute_row(pv3, tv3, AB, Bp, ssim_acc);    // row y0+8 (halo: no l1)

#undef LOADB

    // --- reduction: wave shuffle -> LDS across 4 waves -> one write/block ---
    float s = ssim_acc, l = l1_acc;
#pragma unroll
    for (int off = 32; off > 0; off >>= 1) {
        s += __shfl_down(s, off, 64);
        l += __shfl_down(l, off, 64);
    }
    __shared__ float red_s[NTHREADS / 64];
    __shared__ float red_l[NTHREADS / 64];
    const int wid = tid >> 6, lane = tid & 63;
    if (lane == 0) { red_s[wid] = s; red_l[wid] = l; }
    __syncthreads();
    if (tid == 0) {
        float ss = 0.f, ll = 0.f;
#pragma unroll
        for (int w = 0; w < NTHREADS / 64; ++w) { ss += red_s[w]; ll += red_l[w]; }
        if (MODE == 0) {
            const int bid = blockIdx.z * gridDim.y + blockIdx.y;
            ws[2 * bid]     = ss;   // every slot written every call: no pre-zero
            ws[2 * bid + 1] = ll;
        } else {
            atomicAdd(&ws[0], ss);
            atomicAdd(&ws[1], ll);
        }
    }
}

__global__ void zero_ws_kernel(float* __restrict__ ws) {
    ws[0] = 0.f;
    ws[1] = 0.f;
}

// Sum nblocks (ssim,l1) pairs from ws and emit the final scalar.
__global__ void __launch_bounds__(256)
finalize_partials_kernel(const float* __restrict__ ws, float* __restrict__ out,
                         int nblocks, float inv_total) {
    const int tid = threadIdx.x;
    float s = 0.f, l = 0.f;
    for (int i = tid; i < nblocks; i += 256) {
        s += ws[2 * i];
        l += ws[2 * i + 1];
    }
#pragma unroll
    for (int off = 32; off > 0; off >>= 1) {
        s += __shfl_down(s, off, 64);
        l += __shfl_down(l, off, 64);
    }
    __shared__ float red_s[4], red_l[4];
    const int wid = tid >> 6, lane = tid & 63;
    if (lane == 0) { red_s[wid] = s; red_l[wid] = l; }
    __syncthreads();
    if (tid == 0) {
        float ss = red_s[0] + red_s[1] + red_s[2] + red_s[3];
        float ll = red_l[0] + red_l[1] + red_l[2] + red_l[3];
        out[0] = ALPHA_ * (ss * inv_total) + BETA_ * (ll * inv_total);
    }
}

__global__ void finalize_atomic_kernel(const float* __restrict__ ws,
                                       float* __restrict__ out, float inv_total) {
    out[0] = ALPHA_ * (ws[0] * inv_total) + BETA_ * (ws[1] * inv_total);
}

extern "C" void kernel_launch(void* const* d_in, const int* in_sizes, int n_in,
                              void* d_out, int out_size, void* d_ws, size_t ws_size,
                              hipStream_t stream) {
    const float* pred = (const float*)d_in[0];
    const float* tgt  = (const float*)d_in[1];
    float* ws = (float*)d_ws;

    const int total = in_sizes[0];                 // N * H * W = 16 * 1024 * 1024
    const int nimg  = total / (IMG_W * IMG_H);     // 16
    const int nblk  = nimg * (IMG_H / TH);         // 16 * 128 = 2048
    const float inv_total = 1.0f / (float)total;

    dim3 grid(1, IMG_H / TH, nimg);

    if (ws_size >= (size_t)(2 * nblk) * sizeof(float)) {
        // partials path: no pre-zero, no atomics
        ssim_l1_kernel<0><<<grid, NTHREADS, 0, stream>>>(pred, tgt, ws);
        finalize_partials_kernel<<<1, 256, 0, stream>>>(ws, (float*)d_out,
                                                        nblk, inv_total);
    } else {
        // fallback: atomic accumulation into ws[0..1]
        zero_ws_kernel<<<1, 1, 0, stream>>>(ws);
        ssim_l1_kernel<1><<<grid, NTHREADS, 0, stream>>>(pred, tgt, ws);
        finalize_atomic_kernel<<<1, 1, 0, stream>>>(ws, (float*)d_out, inv_total);
    }
}